// Round 2
// baseline (259.951 us; speedup 1.0000x reference)
//
#include <hip/hip_runtime.h>
#include <hip/hip_bf16.h>

#define IN_C  256
#define OUT_C 256
#define HH 56
#define WW 56
#define NN 32
#define XT_H 58
#define XT_W 64
#define WT_BYTES (8*9*256*32*2)  /* 1,179,648 B */

#define XS_BYTES 24576   /* 6 rows x 64 cols x 32 ic x 2B */
#define WS_BYTES 49152   /* 3 taps x 256 oc x 32 ic x 2B  */
#define LDS_TOTAL (2*XS_BYTES + 2*WS_BYTES)  /* 147456 = 144 KiB */

using short8 = __attribute__((ext_vector_type(8))) short;
using f32x4  = __attribute__((ext_vector_type(4))) float;

__device__ __forceinline__ void gload_lds16(const void* g, void* l) {
  __builtin_amdgcn_global_load_lds((const __attribute__((address_space(1))) void*)g,
                                   (__attribute__((address_space(3))) void*)l,
                                   16, 0, 0);
}

// weight fp32 OIHW -> wt bf16 [chunk(8)][tap(9)][oc(256)][ic5(32)]
__global__ void k_wconv(const float* __restrict__ w, __hip_bfloat16* __restrict__ wt) {
  int idx = blockIdx.x * 256 + threadIdx.x;
  if (idx >= OUT_C * IN_C * 9) return;
  int kw = idx % 3; int t1 = idx / 3;
  int kh = t1 % 3;  int t2 = t1 / 3;
  int ic = t2 % IN_C; int oc = t2 / IN_C;
  int tap = kh * 3 + kw;
  int chunk = ic >> 5, ic5 = ic & 31;
  wt[(((chunk * 9 + tap) * 256 + oc) * 32) + ic5] = __float2bfloat16(w[idx]);
}

// zero the halo cells of xt [n][58][64][256]
__global__ void k_xpad(__hip_bfloat16* __restrict__ xt) {
  int cell = blockIdx.x * 256 + threadIdx.x;
  if (cell >= NN * XT_H * XT_W) return;
  int wp = cell & 63; int t = cell >> 6;
  int hp = t % XT_H;
  if (hp == 0 || hp == 57 || wp == 0 || wp >= 57) {
    int4 z; z.x = 0; z.y = 0; z.z = 0; z.w = 0;
    int4* p = (int4*)(xt + (size_t)cell * 256);
#pragma unroll
    for (int i = 0; i < 32; ++i) p[i] = z;
  }
}

// x fp32 NCHW -> xt bf16 padded NHWC [n][hp=h+1][wp=w+1][ic]
__global__ void k_xconv(const float* __restrict__ x, __hip_bfloat16* __restrict__ xt) {
  __shared__ __hip_bfloat16 tile[64][58];
  int bid = blockIdx.x;
  int icb = bid & 3; int t = bid >> 2;
  int h = t % HH; int n = t / HH;
  for (int e = threadIdx.x; e < 64 * 56; e += 256) {
    int i = e / 56, w = e - i * 56;
    tile[i][w] = __float2bfloat16(x[(((size_t)n * IN_C + icb * 64 + i) * HH + h) * WW + w]);
  }
  __syncthreads();
  for (int e = threadIdx.x; e < 56 * 64; e += 256) {
    int w = e >> 6, i = e & 63;
    xt[((size_t)(n * XT_H + h + 1) * XT_W + (w + 1)) * 256 + icb * 64 + i] = tile[i][w];
  }
}

// main: implicit GEMM conv. block = (n, 4 output rows) = 224 pixels x 256 oc.
// 8 waves: wm = pixel half (112), wn = oc quarter (64).
// LDS: double-buffered x (2x24K) + double-buffered 3-tap weight groups (2x48K).
// Swizzle: within each 64B cell, physical 16B slot = (g + (col>>2)) & 3.
__global__ __launch_bounds__(512, 2) void k_conv(
    const __hip_bfloat16* __restrict__ wt, const __hip_bfloat16* __restrict__ xt,
    const float* __restrict__ bias, float* __restrict__ out) {
  extern __shared__ __align__(16) char lds[];
  char* xs_c = lds;                    // 2 x XS_BYTES: [row6][col64][slot4][16B]
  char* ws_c = lds + 2 * XS_BYTES;     // 2 x WS_BYTES: [tap3][oc256][slot4][16B]

  const int tid  = threadIdx.x;
  const int wid  = tid >> 6, lane = tid & 63;
  const int c    = lane & 15, g = lane >> 4;
  const int wn   = wid & 3,  wm = wid >> 2;
  const int n    = blockIdx.x / 14, q = blockIdx.x % 14;
  const int h0   = q * 4;

  // inverse-swizzle source slot for staging lanes: phys slot l&3 holds logical g
  const int glog = ((lane & 3) - ((lane >> 4) & 3)) & 3;

  // swizzled read offsets for x fragments: [kw][pt]
  int xoffk[3][7];
#pragma unroll
  for (int kw = 0; kw < 3; ++kw)
#pragma unroll
    for (int pt = 0; pt < 7; ++pt) {
      int p = wm * 112 + pt * 16 + c;
      int rp = p / 56, wp = p - rp * 56;
      int col = wp + kw;
      xoffk[kw][pt] = rp * 4096 + col * 64 + (((g + (col >> 2)) & 3) * 16);
    }
  // swizzled weight read offset (oct-invariant: oct*16 ocs keep (oc>>2)&3 == (c>>2)&3)
  const int woffb = (wn * 64 + c) * 64 + (((g + (c >> 2)) & 3) * 16);

  f32x4 acc[4][7];
#pragma unroll
  for (int a = 0; a < 4; ++a)
#pragma unroll
    for (int b = 0; b < 7; ++b) acc[a][b] = (f32x4){0.f, 0.f, 0.f, 0.f};

  const __hip_bfloat16* xtn = xt + (size_t)(n * XT_H + h0) * XT_W * 256;

  // ---- staging helpers (LDS dest is wave-uniform base; lane writes base+l*16) ----
  // x chunk: 24 strips of 1 KiB; 3 per wave. strip s -> row s>>2, col-quad s&3.
  auto stage_x = [&](int buf, int chunk) {
#pragma unroll
    for (int i = 0; i < 3; ++i) {
      int s = wid * 3 + i;
      int row = s >> 2, colq = s & 3;
      const __hip_bfloat16* src = xtn + (size_t)(row * 64 + colq * 16 + (lane >> 2)) * 256
                                      + chunk * 32 + glog * 8;
      gload_lds16(src, xs_c + buf * XS_BYTES + row * 4096 + colq * 1024);
    }
  };
  // 3-tap weight group: 48 strips of 1 KiB; 6 per wave. strip s -> tap3 s>>4, oc16 s&15.
  auto stage_w = [&](int buf, int w9off /* chunk*9 + kh*3 */) {
#pragma unroll
    for (int i = 0; i < 6; ++i) {
      int s = wid * 6 + i;
      const __hip_bfloat16* src = wt + (size_t)((w9off + (s >> 4)) * 256 + (s & 15) * 16 + (lane >> 2)) * 32
                                     + glog * 8;
      gload_lds16(src, ws_c + buf * WS_BYTES + s * 1024);
    }
  };

  // ---- prologue ----
  int wb = 0;
  stage_x(0, 0);
  stage_w(0, 0);
  __syncthreads();

  // ---- main loop: 24 phases, one barrier each; prefetch issued before compute ----
  for (int chunk = 0; chunk < 8; ++chunk) {
    const int xb = chunk & 1;
    const char* xbase = xs_c + xb * XS_BYTES;
#pragma unroll
    for (int kh = 0; kh < 3; ++kh) {
      if (kh < 2) {
        stage_w(wb ^ 1, chunk * 9 + (kh + 1) * 3);
      } else if (chunk < 7) {
        stage_w(wb ^ 1, (chunk + 1) * 9);
        stage_x(xb ^ 1, chunk + 1);
      }
      const char* wbase = ws_c + wb * WS_BYTES;
#pragma unroll
      for (int kw = 0; kw < 3; ++kw) {
        short8 xf[7], wf[4];
#pragma unroll
        for (int pt = 0; pt < 7; ++pt)
          xf[pt] = *(const short8*)(xbase + xoffk[kw][pt] + kh * 4096);
#pragma unroll
        for (int oct = 0; oct < 4; ++oct)
          wf[oct] = *(const short8*)(wbase + kw * 16384 + woffb + oct * 1024);
#pragma unroll
        for (int oct = 0; oct < 4; ++oct)
#pragma unroll
          for (int pt = 0; pt < 7; ++pt)
            acc[oct][pt] = __builtin_amdgcn_mfma_f32_16x16x32_bf16(wf[oct], xf[pt], acc[oct][pt], 0, 0, 0);
      }
      __syncthreads();
      wb ^= 1;
    }
  }

  // ---- epilogue: D row(4g+r)=oc, D col(c)=pixel -> coalesced stores over c ----
  int rp_[7], wp_[7];
#pragma unroll
  for (int pt = 0; pt < 7; ++pt) {
    int p = wm * 112 + pt * 16 + c;
    rp_[pt] = p / 56; wp_[pt] = p - rp_[pt] * 56;
  }
#pragma unroll
  for (int oct = 0; oct < 4; ++oct) {
    const int oc0 = wn * 64 + oct * 16 + 4 * g;
#pragma unroll
    for (int r = 0; r < 4; ++r) {
      const float bv = bias[oc0 + r];
      const size_t obase = ((size_t)n * OUT_C + (oc0 + r)) * (HH * WW);
#pragma unroll
      for (int pt = 0; pt < 7; ++pt)
        out[obase + (size_t)(h0 + rp_[pt]) * 56 + wp_[pt]] = acc[oct][pt][r] + bv;
    }
  }
}

extern "C" void kernel_launch(void* const* d_in, const int* in_sizes, int n_in,
                              void* d_out, int out_size, void* d_ws, size_t ws_size,
                              hipStream_t stream) {
  const float* x    = (const float*)d_in[0];
  const float* w    = (const float*)d_in[1];
  const float* bias = (const float*)d_in[2];
  float* out        = (float*)d_out;

  __hip_bfloat16* wt = (__hip_bfloat16*)d_ws;
  __hip_bfloat16* xt = (__hip_bfloat16*)((char*)d_ws + WT_BYTES);

  hipFuncSetAttribute((const void*)k_conv,
                      hipFuncAttributeMaxDynamicSharedMemorySize, LDS_TOTAL);

  k_wconv<<<(OUT_C * IN_C * 9 + 255) / 256, 256, 0, stream>>>(w, wt);
  k_xpad <<<(NN * XT_H * XT_W + 255) / 256, 256, 0, stream>>>(xt);
  k_xconv<<<NN * HH * 4, 256, 0, stream>>>(x, xt);
  k_conv <<<NN * 14, 512, LDS_TOTAL, stream>>>(wt, xt, bias, out);
}

// Round 3
// 165.282 us; speedup vs baseline: 1.5728x; 1.5728x over previous
//
#include <hip/hip_runtime.h>
#include <hip/hip_bf16.h>

#define IN_C  256
#define OUT_C 256
#define HH 56
#define WW 56
#define NN 32
#define XT_H 58
#define XT_W 64
#define WT_BYTES (8*9*256*32*2)  /* 1,179,648 B */

#define XS_BYTES 24576                      /* 6 rows x 64 cols x 64B  */
#define WS_TAP   16384                      /* 256 oc x 64B            */
#define LDS_TOTAL (2*XS_BYTES + 4*WS_TAP)   /* 114688 = 112 KiB        */

using short8 = __attribute__((ext_vector_type(8))) short;
using f32x4  = __attribute__((ext_vector_type(4))) float;

__device__ __forceinline__ void gload_lds16(const void* g, void* l) {
  __builtin_amdgcn_global_load_lds((const __attribute__((address_space(1))) void*)g,
                                   (__attribute__((address_space(3))) void*)l,
                                   16, 0, 0);
}

#define VMWAIT(N) asm volatile("s_waitcnt vmcnt(" #N ")" ::: "memory")

// weight fp32 OIHW -> wt bf16 [chunk(8)][tap(9)][oc(256)][ic5(32)]
__global__ void k_wconv(const float* __restrict__ w, __hip_bfloat16* __restrict__ wt) {
  int idx = blockIdx.x * 256 + threadIdx.x;
  if (idx >= OUT_C * IN_C * 9) return;
  int kw = idx % 3; int t1 = idx / 3;
  int kh = t1 % 3;  int t2 = t1 / 3;
  int ic = t2 % IN_C; int oc = t2 / IN_C;
  int tap = kh * 3 + kw;
  int chunk = ic >> 5, ic5 = ic & 31;
  wt[(((chunk * 9 + tap) * 256 + oc) * 32) + ic5] = __float2bfloat16(w[idx]);
}

// zero the halo cells of xt [n][58][64][256]
__global__ void k_xpad(__hip_bfloat16* __restrict__ xt) {
  int cell = blockIdx.x * 256 + threadIdx.x;
  if (cell >= NN * XT_H * XT_W) return;
  int wp = cell & 63; int t = cell >> 6;
  int hp = t % XT_H;
  if (hp == 0 || hp == 57 || wp == 0 || wp >= 57) {
    int4 z; z.x = 0; z.y = 0; z.z = 0; z.w = 0;
    int4* p = (int4*)(xt + (size_t)cell * 256);
#pragma unroll
    for (int i = 0; i < 32; ++i) p[i] = z;
  }
}

// x fp32 NCHW -> xt bf16 padded NHWC [n][hp=h+1][wp=w+1][ic]
__global__ void k_xconv(const float* __restrict__ x, __hip_bfloat16* __restrict__ xt) {
  __shared__ __hip_bfloat16 tile[64][58];
  int bid = blockIdx.x;
  int icb = bid & 3; int t = bid >> 2;
  int h = t % HH; int n = t / HH;
  for (int e = threadIdx.x; e < 64 * 56; e += 256) {
    int i = e / 56, w = e - i * 56;
    tile[i][w] = __float2bfloat16(x[(((size_t)n * IN_C + icb * 64 + i) * HH + h) * WW + w]);
  }
  __syncthreads();
  for (int e = threadIdx.x; e < 56 * 64; e += 256) {
    int w = e >> 6, i = e & 63;
    xt[((size_t)(n * XT_H + h + 1) * XT_W + (w + 1)) * 256 + icb * 64 + i] = tile[i][w];
  }
}

// main: implicit GEMM conv. block = (n, 4 output rows) = 224 pixels x 256 oc.
// 8 waves: wm = pixel half (112), wn = oc quarter (64).
// 72 phases (chunk x tap). Per phase: counted vmcnt + ONE raw barrier;
// weight prefetch 3 phases ahead into 4-deep LDS ring; x prefetch 9 phases ahead.
__global__ __launch_bounds__(512, 2) void k_conv(
    const __hip_bfloat16* __restrict__ wt, const __hip_bfloat16* __restrict__ xt,
    const float* __restrict__ bias, float* __restrict__ out) {
  extern __shared__ __align__(16) char lds[];
  char* xs_c = lds;                    // [2][row6][col64][64B]
  char* ws_c = lds + 2 * XS_BYTES;     // [slot4][oc256][64B]

  const int tid  = threadIdx.x;
  const int wid  = tid >> 6, lane = tid & 63;
  const int cc   = lane & 15, g = lane >> 4;
  const int wn   = wid & 3,  wm = wid >> 2;
  const int n    = blockIdx.x / 14, q = blockIdx.x % 14;
  const int h0   = q * 4;

  int xoff[7], rp_[7], wp_[7];
#pragma unroll
  for (int pt = 0; pt < 7; ++pt) {
    int p = wm * 112 + pt * 16 + cc;
    int rp = p / 56, wp = p - rp * 56;
    rp_[pt] = rp; wp_[pt] = wp;
    xoff[pt] = rp * 4096 + wp * 64 + g * 16;
  }
  const int woffb = (wn * 64 + cc) * 64 + g * 16;

  f32x4 acc[4][7];
#pragma unroll
  for (int a = 0; a < 4; ++a)
#pragma unroll
    for (int b = 0; b < 7; ++b) acc[a][b] = (f32x4){0.f, 0.f, 0.f, 0.f};

  const __hip_bfloat16* xtn = xt + (size_t)(n * XT_H + h0) * XT_W * 256;

  // weight tap-block (16 KiB = 16 strips of 1 KiB; 2 per wave)
  auto stage_w = [&](int slot, int tapblk) {
#pragma unroll
    for (int i = 0; i < 2; ++i) {
      int s = wid * 2 + i;
      const __hip_bfloat16* src = wt + (size_t)tapblk * 8192
                                     + (size_t)(s * 16 + (lane >> 2)) * 32 + (lane & 3) * 8;
      gload_lds16(src, ws_c + slot * WS_TAP + s * 1024);
    }
  };
  // x chunk (24 KiB = 24 strips of 1 KiB; 3 per wave)
  auto stage_x = [&](int buf, int ch) {
#pragma unroll
    for (int i = 0; i < 3; ++i) {
      int s = wid * 3 + i;
      int row = s >> 2, colq = s & 3;
      const __hip_bfloat16* src = xtn + (size_t)(row * 64 + colq * 16 + (lane >> 2)) * 256
                                      + ch * 32 + (lane & 3) * 8;
      gload_lds16(src, xs_c + buf * XS_BYTES + row * 4096 + colq * 1024);
    }
  };

  // ---- prologue: x(0) then w(0),w(1),w(2) (queue order matters for vmcnt math) ----
  stage_x(0, 0);
  stage_w(0, 0);
  stage_w(1, 1);
  stage_w(2, 2);

#define PHASE(ch_, tap_, NW_, DOW_, DOX_) do {                                        \
    VMWAIT(NW_);                                                                      \
    __builtin_amdgcn_s_barrier();                                                     \
    if (DOW_) stage_w(((ch_) + (tap_) + 3) & 3, (ch_) * 9 + (tap_) + 3);              \
    if (DOX_) stage_x(((ch_) + 1) & 1, (ch_) + 1);                                    \
    const char* wbase = ws_c + (((ch_) + (tap_)) & 3) * WS_TAP;                       \
    const char* xbase = xs_c + ((ch_) & 1) * XS_BYTES;                                \
    short8 xf[7], wf[4];                                                              \
    _Pragma("unroll")                                                                 \
    for (int pt = 0; pt < 7; ++pt)                                                    \
      xf[pt] = *(const short8*)(xbase + xoff[pt] + ((tap_) / 3) * 4096 + ((tap_) % 3) * 64); \
    _Pragma("unroll")                                                                 \
    for (int oct = 0; oct < 4; ++oct)                                                 \
      wf[oct] = *(const short8*)(wbase + woffb + oct * 1024);                         \
    __builtin_amdgcn_s_setprio(1);                                                    \
    _Pragma("unroll")                                                                 \
    for (int oct = 0; oct < 4; ++oct)                                                 \
      _Pragma("unroll")                                                               \
      for (int pt = 0; pt < 7; ++pt)                                                  \
        acc[oct][pt] = __builtin_amdgcn_mfma_f32_16x16x32_bf16(wf[oct], xf[pt], acc[oct][pt], 0, 0, 0); \
    __builtin_amdgcn_s_setprio(0);                                                    \
  } while (0)

  // chunks 0..6: N per tap {4,7,7,7,4,4,4,4,4}; x(ch+1) issued at tap 0
  for (int ch = 0; ch < 7; ++ch) {
    PHASE(ch, 0, 4, 1, 1);
    PHASE(ch, 1, 7, 1, 0);
    PHASE(ch, 2, 7, 1, 0);
    PHASE(ch, 3, 7, 1, 0);
    PHASE(ch, 4, 4, 1, 0);
    PHASE(ch, 5, 4, 1, 0);
    PHASE(ch, 6, 4, 1, 0);
    PHASE(ch, 7, 4, 1, 0);
    PHASE(ch, 8, 4, 1, 0);
  }
  // peeled chunk 7: w issues stop at tap 5; drain N = {...,4,2,0}
  PHASE(7, 0, 4, 1, 0);
  PHASE(7, 1, 4, 1, 0);
  PHASE(7, 2, 4, 1, 0);
  PHASE(7, 3, 4, 1, 0);
  PHASE(7, 4, 4, 1, 0);
  PHASE(7, 5, 4, 1, 0);
  PHASE(7, 6, 4, 0, 0);
  PHASE(7, 7, 2, 0, 0);
  PHASE(7, 8, 0, 0, 0);
#undef PHASE

  // ---- epilogue: D row(4g+r)=oc, D col(cc)=pixel -> coalesced stores over cc ----
#pragma unroll
  for (int oct = 0; oct < 4; ++oct) {
    const int oc0 = wn * 64 + oct * 16 + 4 * g;
#pragma unroll
    for (int r = 0; r < 4; ++r) {
      const float bv = bias[oc0 + r];
      const size_t obase = ((size_t)n * OUT_C + (oc0 + r)) * (HH * WW);
#pragma unroll
      for (int pt = 0; pt < 7; ++pt)
        out[obase + (size_t)(h0 + rp_[pt]) * 56 + wp_[pt]] = acc[oct][pt][r] + bv;
    }
  }
}

extern "C" void kernel_launch(void* const* d_in, const int* in_sizes, int n_in,
                              void* d_out, int out_size, void* d_ws, size_t ws_size,
                              hipStream_t stream) {
  const float* x    = (const float*)d_in[0];
  const float* w    = (const float*)d_in[1];
  const float* bias = (const float*)d_in[2];
  float* out        = (float*)d_out;

  __hip_bfloat16* wt = (__hip_bfloat16*)d_ws;
  __hip_bfloat16* xt = (__hip_bfloat16*)((char*)d_ws + WT_BYTES);

  hipFuncSetAttribute((const void*)k_conv,
                      hipFuncAttributeMaxDynamicSharedMemorySize, LDS_TOTAL);

  k_wconv<<<(OUT_C * IN_C * 9 + 255) / 256, 256, 0, stream>>>(w, wt);
  k_xpad <<<(NN * XT_H * XT_W + 255) / 256, 256, 0, stream>>>(xt);
  k_xconv<<<NN * HH * 4, 256, 0, stream>>>(x, xt);
  k_conv <<<NN * 14, 512, LDS_TOTAL, stream>>>(wt, xt, bias, out);
}

// Round 4
// 154.215 us; speedup vs baseline: 1.6856x; 1.0718x over previous
//
#include <hip/hip_runtime.h>
#include <hip/hip_bf16.h>

#define IN_C  256
#define OUT_C 256
#define HH 56
#define WW 56
#define NN 32
#define XT_H 58
#define XT_W 64
#define WT_BYTES (8*9*256*32*2)  /* 1,179,648 B */

#define XS_BYTES 24576                      /* 6 rows x 64 cols x 64B  */
#define WS_TAP   8192                       /* 128 oc x 64B            */
#define LDS_TOTAL (2*XS_BYTES + 4*WS_TAP)   /* 81920 = 80 KiB -> 2 blocks/CU */

using short8 = __attribute__((ext_vector_type(8))) short;
using f32x4  = __attribute__((ext_vector_type(4))) float;

__device__ __forceinline__ void gload_lds16(const void* g, void* l) {
  __builtin_amdgcn_global_load_lds((const __attribute__((address_space(1))) void*)g,
                                   (__attribute__((address_space(3))) void*)l,
                                   16, 0, 0);
}

#define VMWAIT(N) asm volatile("s_waitcnt vmcnt(" #N ")" ::: "memory")

// weight fp32 OIHW -> wt bf16 [chunk(8)][tap(9)][oc(256)][ic5(32)]
__global__ void k_wconv(const float* __restrict__ w, __hip_bfloat16* __restrict__ wt) {
  int idx = blockIdx.x * 256 + threadIdx.x;
  if (idx >= OUT_C * IN_C * 9) return;
  int kw = idx % 3; int t1 = idx / 3;
  int kh = t1 % 3;  int t2 = t1 / 3;
  int ic = t2 % IN_C; int oc = t2 / IN_C;
  int tap = kh * 3 + kw;
  int chunk = ic >> 5, ic5 = ic & 31;
  wt[(((chunk * 9 + tap) * 256 + oc) * 32) + ic5] = __float2bfloat16(w[idx]);
}

// zero the halo cells of xt [n][58][64][256]
__global__ void k_xpad(__hip_bfloat16* __restrict__ xt) {
  int cell = blockIdx.x * 256 + threadIdx.x;
  if (cell >= NN * XT_H * XT_W) return;
  int wp = cell & 63; int t = cell >> 6;
  int hp = t % XT_H;
  if (hp == 0 || hp == 57 || wp == 0 || wp >= 57) {
    int4 z; z.x = 0; z.y = 0; z.z = 0; z.w = 0;
    int4* p = (int4*)(xt + (size_t)cell * 256);
#pragma unroll
    for (int i = 0; i < 32; ++i) p[i] = z;
  }
}

// x fp32 NCHW -> xt bf16 padded NHWC [n][hp=h+1][wp=w+1][ic]
__global__ void k_xconv(const float* __restrict__ x, __hip_bfloat16* __restrict__ xt) {
  __shared__ __hip_bfloat16 tile[64][58];
  int bid = blockIdx.x;
  int icb = bid & 3; int t = bid >> 2;
  int h = t % HH; int n = t / HH;
  for (int e = threadIdx.x; e < 64 * 56; e += 256) {
    int i = e / 56, w = e - i * 56;
    tile[i][w] = __float2bfloat16(x[(((size_t)n * IN_C + icb * 64 + i) * HH + h) * WW + w]);
  }
  __syncthreads();
  for (int e = threadIdx.x; e < 56 * 64; e += 256) {
    int w = e >> 6, i = e & 63;
    xt[((size_t)(n * XT_H + h + 1) * XT_W + (w + 1)) * 256 + icb * 64 + i] = tile[i][w];
  }
}

// main: implicit GEMM conv. block = 4 waves (256 thr), tile 224 px x 128 oc.
// Per wave: 112 px x 64 oc (wm = wid>>1 pixel half, wn = wid&1 oc half).
// 80 KiB LDS -> 2 independent blocks co-resident per CU (independent barrier
// groups keep the MFMA pipe fed through each other's barrier/stage windows).
// 72 phases; counted vmcnt + one raw barrier per phase; 4-deep w ring.
__global__ __launch_bounds__(256, 2) void k_conv(
    const __hip_bfloat16* __restrict__ wt, const __hip_bfloat16* __restrict__ xt,
    const float* __restrict__ bias, float* __restrict__ out) {
  extern __shared__ __align__(16) char lds[];
  char* xs_c = lds;                    // [2][row6][col64][64B]
  char* ws_c = lds + 2 * XS_BYTES;     // [slot4][oc128][64B]

  const int tid  = threadIdx.x;
  const int wid  = tid >> 6, lane = tid & 63;
  const int cc   = lane & 15, g = lane >> 4;
  const int wn   = wid & 1,  wm = wid >> 1;

  // XCD-bijective swizzle (896 % 8 == 0): same-XCD blocks get contiguous work
  const int work = (blockIdx.x & 7) * 112 + (blockIdx.x >> 3);
  const int n  = work / 28;
  const int rem = work - n * 28;
  const int q  = rem >> 1, oh = rem & 1;
  const int h0 = q * 4;

  int xoff[7], rp_[7], wp_[7];
#pragma unroll
  for (int pt = 0; pt < 7; ++pt) {
    int p = wm * 112 + pt * 16 + cc;
    int rp = p / 56, wp = p - rp * 56;
    rp_[pt] = rp; wp_[pt] = wp;
    xoff[pt] = rp * 4096 + wp * 64 + g * 16;
  }
  const int woffb = (wn * 64 + cc) * 64 + g * 16;

  f32x4 acc[4][7];
#pragma unroll
  for (int a = 0; a < 4; ++a)
#pragma unroll
    for (int b = 0; b < 7; ++b) acc[a][b] = (f32x4){0.f, 0.f, 0.f, 0.f};

  const __hip_bfloat16* xtn = xt + (size_t)(n * XT_H + h0) * XT_W * 256;

  // weight tap-block for this oc-half: 8 KiB = 8 strips of 1 KiB; 2 per wave
  auto stage_w = [&](int slot, int tapblk) {
#pragma unroll
    for (int i = 0; i < 2; ++i) {
      int s = wid * 2 + i;
      const __hip_bfloat16* src = wt + (size_t)tapblk * 8192
                                     + (size_t)(oh * 128 + s * 16 + (lane >> 2)) * 32
                                     + (lane & 3) * 8;
      gload_lds16(src, ws_c + slot * WS_TAP + s * 1024);
    }
  };
  // x chunk (24 KiB = 24 strips of 1 KiB; 6 per wave)
  auto stage_x = [&](int buf, int ch) {
#pragma unroll
    for (int i = 0; i < 6; ++i) {
      int s = wid * 6 + i;
      int row = s >> 2, colq = s & 3;
      const __hip_bfloat16* src = xtn + (size_t)(row * 64 + colq * 16 + (lane >> 2)) * 256
                                      + ch * 32 + (lane & 3) * 8;
      gload_lds16(src, xs_c + buf * XS_BYTES + row * 4096 + colq * 1024);
    }
  };

  // ---- prologue (queue order matters for vmcnt FIFO math) ----
  stage_x(0, 0);
  stage_w(0, 0);
  stage_w(1, 1);
  stage_w(2, 2);

#define PHASE(ch_, tap_, NW_, DOW_, DOX_) do {                                        \
    VMWAIT(NW_);                                                                      \
    __builtin_amdgcn_s_barrier();                                                     \
    if (DOW_) stage_w(((ch_) + (tap_) + 3) & 3, (ch_) * 9 + (tap_) + 3);              \
    if (DOX_) stage_x(((ch_) + 1) & 1, (ch_) + 1);                                    \
    const char* wbase = ws_c + (((ch_) + (tap_)) & 3) * WS_TAP;                       \
    const char* xbase = xs_c + ((ch_) & 1) * XS_BYTES;                                \
    short8 xf[7], wf[4];                                                              \
    _Pragma("unroll")                                                                 \
    for (int pt = 0; pt < 7; ++pt)                                                    \
      xf[pt] = *(const short8*)(xbase + xoff[pt] + ((tap_) / 3) * 4096 + ((tap_) % 3) * 64); \
    _Pragma("unroll")                                                                 \
    for (int oct = 0; oct < 4; ++oct)                                                 \
      wf[oct] = *(const short8*)(wbase + woffb + oct * 1024);                         \
    __builtin_amdgcn_s_setprio(1);                                                    \
    _Pragma("unroll")                                                                 \
    for (int oct = 0; oct < 4; ++oct)                                                 \
      _Pragma("unroll")                                                               \
      for (int pt = 0; pt < 7; ++pt)                                                  \
        acc[oct][pt] = __builtin_amdgcn_mfma_f32_16x16x32_bf16(wf[oct], xf[pt], acc[oct][pt], 0, 0, 0); \
    __builtin_amdgcn_s_setprio(0);                                                    \
  } while (0)

  // chunks 0..6: vmcnt N per tap {4,10,10,10,4,4,4,4,4}; x(ch+1) issued at tap 0
  for (int ch = 0; ch < 7; ++ch) {
    PHASE(ch, 0, 4, 1, 1);
    PHASE(ch, 1, 10, 1, 0);
    PHASE(ch, 2, 10, 1, 0);
    PHASE(ch, 3, 10, 1, 0);
    PHASE(ch, 4, 4, 1, 0);
    PHASE(ch, 5, 4, 1, 0);
    PHASE(ch, 6, 4, 1, 0);
    PHASE(ch, 7, 4, 1, 0);
    PHASE(ch, 8, 4, 1, 0);
  }
  // peeled chunk 7: w issues stop after tap 5; drain {...,4,2,0}
  PHASE(7, 0, 4, 1, 0);
  PHASE(7, 1, 4, 1, 0);
  PHASE(7, 2, 4, 1, 0);
  PHASE(7, 3, 4, 1, 0);
  PHASE(7, 4, 4, 1, 0);
  PHASE(7, 5, 4, 1, 0);
  PHASE(7, 6, 4, 0, 0);
  PHASE(7, 7, 2, 0, 0);
  PHASE(7, 8, 0, 0, 0);
#undef PHASE

  // ---- epilogue: D row(4g+r)=oc, D col(cc)=pixel -> coalesced stores over cc ----
#pragma unroll
  for (int oct = 0; oct < 4; ++oct) {
    const int oc0 = oh * 128 + wn * 64 + oct * 16 + 4 * g;
#pragma unroll
    for (int r = 0; r < 4; ++r) {
      const float bv = bias[oc0 + r];
      const size_t obase = ((size_t)n * OUT_C + (oc0 + r)) * (HH * WW);
#pragma unroll
      for (int pt = 0; pt < 7; ++pt)
        out[obase + (size_t)(h0 + rp_[pt]) * 56 + wp_[pt]] = acc[oct][pt][r] + bv;
    }
  }
}

extern "C" void kernel_launch(void* const* d_in, const int* in_sizes, int n_in,
                              void* d_out, int out_size, void* d_ws, size_t ws_size,
                              hipStream_t stream) {
  const float* x    = (const float*)d_in[0];
  const float* w    = (const float*)d_in[1];
  const float* bias = (const float*)d_in[2];
  float* out        = (float*)d_out;

  __hip_bfloat16* wt = (__hip_bfloat16*)d_ws;
  __hip_bfloat16* xt = (__hip_bfloat16*)((char*)d_ws + WT_BYTES);

  hipFuncSetAttribute((const void*)k_conv,
                      hipFuncAttributeMaxDynamicSharedMemorySize, LDS_TOTAL);

  k_wconv<<<(OUT_C * IN_C * 9 + 255) / 256, 256, 0, stream>>>(w, wt);
  k_xpad <<<(NN * XT_H * XT_W + 255) / 256, 256, 0, stream>>>(xt);
  k_xconv<<<NN * HH * 4, 256, 0, stream>>>(x, xt);
  k_conv <<<NN * 14 * 2, 256, LDS_TOTAL, stream>>>(wt, xt, bias, out);
}